// Round 1
// baseline (1081.766 us; speedup 1.0000x reference)
//
#include <hip/hip_runtime.h>
#include <hip/hip_bf16.h>
#include <stdint.h>

#define IN_F 4096
#define OUT_F 4096
#define NC 32
#define NCLUST 32
#define SUBD 128
#define MROWS 8192

typedef __attribute__((ext_vector_type(8))) short bf16x8;
typedef __attribute__((ext_vector_type(4))) float f32x4;

// ---------------- workspace layout (bytes) ----------------
#define OFF_CMASK ((size_t)0)                 // 32 * 4
#define OFF_QTILE ((size_t)256)               // 64 * 4
#define OFF_QMASK ((size_t)1024)              // 8192 * 4
#define OFF_CW    ((size_t)65536)             // 32*4096*4 = 512 KB
#define OFF_XB    ((size_t)1 << 20)           // 8192*4096*2 = 64 MB
#define OFF_WB    (((size_t)1 << 20) + (size_t)MROWS * IN_F * 2)  // 32 MB
// total ~97 MB

__device__ __forceinline__ void gload_lds16(const void* g, void* l) {
  __builtin_amdgcn_global_load_lds(
      (const __attribute__((address_space(1))) void*)g,
      (__attribute__((address_space(3))) void*)l, 16, 0, 0);
}

// ---------------- K0: expand centroid weight matrix cw[j][i] (fp32) + zero masks ----------------
__global__ void k0_expand_cw(const float* __restrict__ codebooks,
                             const int* __restrict__ centroids,
                             float* __restrict__ cw,
                             int* __restrict__ cmask, int* __restrict__ qtile) {
  int gid = blockIdx.x * 256 + threadIdx.x;
  int e0 = gid * 4;                 // 4 contiguous elements, never cross a 128-subblock
  int j = e0 >> 12;                 // cluster row 0..31
  int i = e0 & 4095;                // feature col
  int c = i >> 7;
  int s = i & 127;
  int idx = centroids[c * NCLUST + j];
  float4 v = *(const float4*)&codebooks[((size_t)(c * 256 + idx)) * SUBD + s];
  *(float4*)&cw[(size_t)j * IN_F + i] = v;
  if (blockIdx.x == 0) {
    if (threadIdx.x < 32) cmask[threadIdx.x] = 0;
    else if (threadIdx.x < 96) qtile[threadIdx.x - 32] = 0;
  }
}

// ---------------- K1: fused x->bf16 convert + routing dots + LN + softmax + masks ----------------
// block = 256 threads = 8 rows x 32 clusters. fp32 throughout (mask decisions are precision-sensitive).
__global__ void k1_dots(const float* __restrict__ x,
                        const float* __restrict__ cw,
                        const float* __restrict__ lnw,
                        __hip_bfloat16* __restrict__ xb,
                        int* __restrict__ qmask, int* __restrict__ cmask,
                        int* __restrict__ qtile) {
  __shared__ float xs[8][512];
  const int tid = threadIdx.x;
  const int r = tid >> 5;   // row within block (0..7)
  const int c = tid & 31;   // cluster
  const size_t row0 = (size_t)blockIdx.x * 8;
  float acc = 0.f;
  for (int k0 = 0; k0 < IN_F; k0 += 512) {
    __syncthreads();
    #pragma unroll
    for (int it = 0; it < 16; ++it) {
      int idx = it * 256 + tid;
      int rr = idx >> 9, cc = idx & 511;
      float v = x[(row0 + rr) * IN_F + k0 + cc];
      xs[rr][cc] = v;
      xb[(row0 + rr) * IN_F + k0 + cc] = __float2bfloat16(v);
    }
    __syncthreads();
    const float* cwrow = cw + (size_t)c * IN_F + k0;
    #pragma unroll 4
    for (int kk = 0; kk < 512; kk += 4) {
      float4 xv = *(const float4*)&xs[r][kk];
      float4 wv = *(const float4*)&cwrow[kk];
      acc = fmaf(xv.x, wv.x, acc);
      acc = fmaf(xv.y, wv.y, acc);
      acc = fmaf(xv.z, wv.z, acc);
      acc = fmaf(xv.w, wv.w, acc);
    }
  }
  // 32-lane subgroup reductions (masks <32 stay within wave64 halves)
  float s1 = acc;
  for (int m = 1; m < 32; m <<= 1) s1 += __shfl_xor(s1, m);
  float mu = s1 * (1.f / 32.f);
  float dv = acc - mu;
  float s2 = dv * dv;
  for (int m = 1; m < 32; m <<= 1) s2 += __shfl_xor(s2, m);
  float var = s2 * (1.f / 32.f);
  float nd = dv * (1.f / sqrtf(var + 1e-5f)) * lnw[c];
  float mx = nd;
  for (int m = 1; m < 32; m <<= 1) mx = fmaxf(mx, __shfl_xor(mx, m));
  float e = expf(nd - mx);
  float se = e;
  for (int m = 1; m < 32; m <<= 1) se += __shfl_xor(se, m);
  bool hit = (e / se) > 0.5f;
  if (hit) atomicOr(&cmask[c], 1);
  int h = hit ? 1 : 0;
  for (int m = 1; m < 32; m <<= 1) h |= __shfl_xor(h, m);
  if (c == 0) {
    size_t row = row0 + r;
    qmask[row] = h;
    if (h) atomicOr(&qtile[row >> 7], 1);
  }
}

// ---------------- K2: expand W to bf16, row-major [OUT_F][IN_F] ----------------
__global__ void k2_expand_w(const float* __restrict__ codebooks,
                            const int* __restrict__ codes,
                            __hip_bfloat16* __restrict__ wb) {
  const int o = blockIdx.x;
  const int tid = threadIdx.x;
  #pragma unroll
  for (int it = 0; it < 2; ++it) {
    int i0 = (it * 256 + tid) * 8;   // 8 contiguous, within one 128-subblock
    int c = i0 >> 7;
    int s = i0 & 127;
    int idx = codes[c * OUT_F + o];
    const float* src = codebooks + ((size_t)(c * 256 + idx)) * SUBD + s;
    float4 v0 = *(const float4*)src;
    float4 v1 = *(const float4*)(src + 4);
    union { __hip_bfloat16 b[8]; uint4 q; } u;
    u.b[0] = __float2bfloat16(v0.x); u.b[1] = __float2bfloat16(v0.y);
    u.b[2] = __float2bfloat16(v0.z); u.b[3] = __float2bfloat16(v0.w);
    u.b[4] = __float2bfloat16(v1.x); u.b[5] = __float2bfloat16(v1.y);
    u.b[6] = __float2bfloat16(v1.z); u.b[7] = __float2bfloat16(v1.w);
    *(uint4*)&wb[(size_t)o * IN_F + i0] = u.q;
  }
}

// ---------------- K3: bf16 MFMA GEMM with masked epilogue ----------------
// m97 structure: 128x128 tile, BK=64, 4 waves (2x2), each wave 4x4 frags of 16x16x32.
#define BM 128
#define BN 128
#define BKK 64

__global__ __launch_bounds__(256) void k3_gemm(
    const __hip_bfloat16* __restrict__ A,   // xb [8192][4096]
    const __hip_bfloat16* __restrict__ B,   // wb [4096][4096] (B^T layout: row = out col)
    const float* __restrict__ bias,
    const int* __restrict__ qmask, const int* __restrict__ cmask,
    const int* __restrict__ qtile,
    float* __restrict__ out) {
  __shared__ __hip_bfloat16 As[BM][BKK];
  __shared__ __hip_bfloat16 Bs[BN][BKK];
  const int tid = threadIdx.x;
  const int bid = blockIdx.x;
  // XCD-aware swizzle (2048 % 8 == 0 -> bijective)
  const int cpx = 2048 >> 3;
  const int swz = (bid & 7) * cpx + (bid >> 3);
  const int bm = swz >> 5;   // 0..63 (row tile)
  const int bn = swz & 31;   // 0..31 (col tile == cluster id, since BN == CLS == 128)

  // early-out: dead cluster column-block or fully-inactive row-block
  if (cmask[bn] == 0 || qtile[bm] == 0) {
    float4 z = make_float4(0.f, 0.f, 0.f, 0.f);
    for (int i = tid; i < BM * BN / 4; i += 256) {
      int rr = i >> 5;
      int cc = (i & 31) << 2;
      *(float4*)&out[((size_t)(bm * BM + rr)) * OUT_F + bn * BN + cc] = z;
    }
    return;
  }

  const int w = tid >> 6, l = tid & 63;
  const int wm = w >> 1, wn = w & 1;
  const int lr = l & 15;
  const int lk = (l >> 4) * 8;

  f32x4 zz = {0.f, 0.f, 0.f, 0.f};
  f32x4 acc[4][4];
  #pragma unroll
  for (int mi = 0; mi < 4; ++mi)
    #pragma unroll
    for (int ni = 0; ni < 4; ++ni) acc[mi][ni] = zz;

  const __hip_bfloat16* Ag = A + ((size_t)bm * BM) * IN_F;
  const __hip_bfloat16* Bg = B + ((size_t)bn * BN) * IN_F;

  for (int k0 = 0; k0 < IN_F; k0 += BKK) {
    // stage A,B tiles: linear LDS, dest = wave-uniform base + lane*16
    #pragma unroll
    for (int i = 0; i < 4; ++i) {
      int chunk = i * 256 + tid;
      int rowa = chunk >> 3;
      int cola = (chunk & 7) * 8;
      gload_lds16(Ag + (size_t)rowa * IN_F + k0 + cola, &As[rowa][cola]);
    }
    #pragma unroll
    for (int i = 0; i < 4; ++i) {
      int chunk = i * 256 + tid;
      int rowb = chunk >> 3;
      int colb = (chunk & 7) * 8;
      gload_lds16(Bg + (size_t)rowb * IN_F + k0 + colb, &Bs[rowb][colb]);
    }
    __syncthreads();
    #pragma unroll
    for (int kk = 0; kk < BKK; kk += 32) {
      bf16x8 af[4], bfr[4];
      #pragma unroll
      for (int mi = 0; mi < 4; ++mi)
        af[mi] = *(const bf16x8*)&As[wm * 64 + mi * 16 + lr][kk + lk];
      #pragma unroll
      for (int ni = 0; ni < 4; ++ni)
        bfr[ni] = *(const bf16x8*)&Bs[wn * 64 + ni * 16 + lr][kk + lk];
      #pragma unroll
      for (int mi = 0; mi < 4; ++mi)
        #pragma unroll
        for (int ni = 0; ni < 4; ++ni)
          acc[mi][ni] = __builtin_amdgcn_mfma_f32_16x16x32_bf16(
              af[mi], bfr[ni], acc[mi][ni], 0, 0, 0);
    }
    __syncthreads();
  }

  // epilogue: +bias, apply qmask (cmask==1 for whole tile here), store fp32
  const int mb = bm * BM + wm * 64;
  const int nb = bn * BN + wn * 64;
  #pragma unroll
  for (int mi = 0; mi < 4; ++mi) {
    #pragma unroll
    for (int j = 0; j < 4; ++j) {
      int rrow = mb + mi * 16 + (l >> 4) * 4 + j;
      float qm = qmask[rrow] ? 1.f : 0.f;
      #pragma unroll
      for (int ni = 0; ni < 4; ++ni) {
        int col = nb + ni * 16 + lr;
        out[(size_t)rrow * OUT_F + col] = (acc[mi][ni][j] + bias[col]) * qm;
      }
    }
  }
}

extern "C" void kernel_launch(void* const* d_in, const int* in_sizes, int n_in,
                              void* d_out, int out_size, void* d_ws, size_t ws_size,
                              hipStream_t stream) {
  const float* x = (const float*)d_in[0];
  const float* codebooks = (const float*)d_in[1];
  const float* bias = (const float*)d_in[2];
  const float* lnw = (const float*)d_in[3];
  const int* codes = (const int*)d_in[4];       // [32][4096]
  const int* centroids = (const int*)d_in[5];   // [32][32]
  float* out = (float*)d_out;

  char* ws = (char*)d_ws;
  int* cmask = (int*)(ws + OFF_CMASK);
  int* qtile = (int*)(ws + OFF_QTILE);
  int* qmask = (int*)(ws + OFF_QMASK);
  float* cw = (float*)(ws + OFF_CW);
  __hip_bfloat16* xb = (__hip_bfloat16*)(ws + OFF_XB);
  __hip_bfloat16* wb = (__hip_bfloat16*)(ws + OFF_WB);

  hipLaunchKernelGGL(k0_expand_cw, dim3(128), dim3(256), 0, stream,
                     codebooks, centroids, cw, cmask, qtile);
  hipLaunchKernelGGL(k1_dots, dim3(1024), dim3(256), 0, stream,
                     x, cw, lnw, xb, qmask, cmask, qtile);
  hipLaunchKernelGGL(k2_expand_w, dim3(4096), dim3(256), 0, stream,
                     codebooks, codes, wb);
  hipLaunchKernelGGL(k3_gemm, dim3(2048), dim3(256), 0, stream,
                     xb, wb, bias, qmask, cmask, qtile, out);
}

// Round 3
// 680.260 us; speedup vs baseline: 1.5902x; 1.5902x over previous
//
#include <hip/hip_runtime.h>
#include <hip/hip_bf16.h>
#include <stdint.h>

#define IN_F 4096
#define OUT_F 4096
#define NCLUST 32
#define MROWS 8192

typedef __attribute__((ext_vector_type(8))) short bf16x8;
typedef __attribute__((ext_vector_type(4))) float f32x4;

// ---------------- workspace layout (bytes) ----------------
#define OFF_CMASK ((size_t)0)                 // 32 * 4
#define OFF_QTILE ((size_t)256)               // 64 * 4
#define OFF_QMASK ((size_t)1024)              // 8192 * 4
#define OFF_WHI   ((size_t)65536)             // 128 ksteps * 2 ct * 64 lanes * 16B = 256 KB
#define OFF_WLO   ((size_t)(65536 + 262144))  // 256 KB
#define OFF_XB    ((size_t)1 << 20)           // 8192*4096*2 = 64 MB
#define OFF_WB    (((size_t)1 << 20) + (size_t)MROWS * IN_F * 2)  // 32 MB

__device__ __forceinline__ void gload_lds16(const void* g, void* l) {
  __builtin_amdgcn_global_load_lds(
      (const __attribute__((address_space(1))) void*)g,
      (__attribute__((address_space(3))) void*)l, 16, 0, 0);
}

// ---------------- K0b: precompute cw B-fragments (hi/lo bf16) + zero masks ----------------
// Fragment layout for mfma_f32_16x16x32_bf16 B-operand (verified by round-1 K3):
// col = lane&15, k = 8*(lane>>4) + j (j=0..7). frag[(kstep*2+ctile)*64 + lane] = 8 bf16.
__global__ void k0b_fragw(const float* __restrict__ codebooks,
                          const int* __restrict__ centroids,
                          uint4* __restrict__ whi, uint4* __restrict__ wlo,
                          int* __restrict__ cmask, int* __restrict__ qtile) {
  int gid = blockIdx.x * 256 + threadIdx.x;   // [0, 16384)
  int l = gid & 63;
  int ct = (gid >> 6) & 1;
  int ks = gid >> 7;                           // 0..127 (k-step of 32)
  int c = ct * 16 + (l & 15);                  // cluster 0..31
  int k0 = ks * 32 + 8 * (l >> 4);             // 8-aligned
  int sub = k0 >> 7;                           // codebook sub-block
  int off = k0 & 127;
  int idx = centroids[sub * 32 + c];
  const float* src = codebooks + ((size_t)(sub * 256 + idx)) * 128 + off;
  float4 v0 = *(const float4*)src;
  float4 v1 = *(const float4*)(src + 4);
  float f[8] = {v0.x, v0.y, v0.z, v0.w, v1.x, v1.y, v1.z, v1.w};
  union { __hip_bfloat16 b[8]; uint4 q; } uh, ul;
  #pragma unroll
  for (int i = 0; i < 8; ++i) {
    __hip_bfloat16 h = __float2bfloat16(f[i]);
    uh.b[i] = h;
    ul.b[i] = __float2bfloat16(f[i] - __bfloat162float(h));
  }
  whi[gid] = uh.q;
  wlo[gid] = ul.q;
  if (gid < 32) cmask[gid] = 0;
  else if (gid < 96) qtile[gid - 32] = 0;
}

// ---------------- K1: fused x->bf16 convert + MFMA routing dots + LN + softmax + masks ----------------
// 256 blocks x 256 threads; block owns 32 rows. K-chunks of 256, k-split over 4 waves.
// dots = hi*whi + hi*wlo + lo*whi  (two-term bf16 split; error ~1e-5 relative).
__global__ __launch_bounds__(256) void k1_dots(
    const float* __restrict__ x,
    const uint4* __restrict__ whi4, const uint4* __restrict__ wlo4,
    const float* __restrict__ lnw,
    __hip_bfloat16* __restrict__ xb,
    int* __restrict__ qmask, int* __restrict__ cmask, int* __restrict__ qtile) {
  __shared__ __align__(16) float xsf[32 * 256];   // 32 rows x 256 k, XOR-swizzled
  __shared__ float part[4][32][32];               // per-wave dot partials
  const int t = threadIdx.x;
  const int wv = t >> 6;          // wave 0..3
  const int l = t & 63;
  const size_t row0 = (size_t)blockIdx.x * 32;
  const float* xg = x + row0 * IN_F;
  const bf16x8* whif = (const bf16x8*)whi4;
  const bf16x8* wlof = (const bf16x8*)wlo4;

  f32x4 zz = {0.f, 0.f, 0.f, 0.f};
  f32x4 acc[2][2];
  acc[0][0] = zz; acc[0][1] = zz; acc[1][0] = zz; acc[1][1] = zz;

  const int col = (t & 63) * 4;   // staging column (float index)
  float4 reg[8];
  // prologue: load chunk 0
  #pragma unroll
  for (int j = 0; j < 8; ++j)
    reg[j] = *(const float4*)&xg[(size_t)(4 * j + wv) * IN_F + col];

  for (int ch = 0; ch < 16; ++ch) {
    // write staged regs -> LDS (swizzled) + bf16 convert -> xb (coalesced)
    #pragma unroll
    for (int j = 0; j < 8; ++j) {
      int row = 4 * j + wv;
      int sw = (row & 7) << 2;
      *(float4*)&xsf[row * 256 + (col ^ sw)] = reg[j];
      union { __hip_bfloat16 b[4]; uint2 q; } u;
      u.b[0] = __float2bfloat16(reg[j].x);
      u.b[1] = __float2bfloat16(reg[j].y);
      u.b[2] = __float2bfloat16(reg[j].z);
      u.b[3] = __float2bfloat16(reg[j].w);
      *(uint2*)&xb[(row0 + row) * IN_F + ch * 256 + col] = u.q;
    }
    // issue next chunk's loads (in flight under compute)
    if (ch + 1 < 16) {
      #pragma unroll
      for (int j = 0; j < 8; ++j)
        reg[j] = *(const float4*)&xg[(size_t)(4 * j + wv) * IN_F + (ch + 1) * 256 + col];
    }
    __syncthreads();
    // compute: this wave covers k in [wv*64, wv*64+64) of the chunk = 2 k-steps of 32
    #pragma unroll
    for (int s = 0; s < 2; ++s) {
      int kk = wv * 64 + s * 32 + 8 * (l >> 4);
      int gk = ch * 8 + wv * 2 + s;           // global k-step 0..127
      bf16x8 ahi[2], alo[2];
      #pragma unroll
      for (int rt = 0; rt < 2; ++rt) {
        int row = rt * 16 + (l & 15);
        int sw = (row & 7) << 2;
        float4 f0 = *(const float4*)&xsf[row * 256 + (kk ^ sw)];
        float4 f1 = *(const float4*)&xsf[row * 256 + ((kk ^ sw) ^ 4)];
        float f[8] = {f0.x, f0.y, f0.z, f0.w, f1.x, f1.y, f1.z, f1.w};
        union { __hip_bfloat16 b[8]; bf16x8 v; } uh, ul;
        #pragma unroll
        for (int i = 0; i < 8; ++i) {
          __hip_bfloat16 h = __float2bfloat16(f[i]);
          uh.b[i] = h;
          ul.b[i] = __float2bfloat16(f[i] - __bfloat162float(h));
        }
        ahi[rt] = uh.v; alo[rt] = ul.v;
      }
      #pragma unroll
      for (int ct = 0; ct < 2; ++ct) {
        bf16x8 bh = whif[(gk * 2 + ct) * 64 + l];
        bf16x8 bl = wlof[(gk * 2 + ct) * 64 + l];
        #pragma unroll
        for (int rt = 0; rt < 2; ++rt) {
          acc[rt][ct] = __builtin_amdgcn_mfma_f32_16x16x32_bf16(ahi[rt], bh, acc[rt][ct], 0, 0, 0);
          acc[rt][ct] = __builtin_amdgcn_mfma_f32_16x16x32_bf16(ahi[rt], bl, acc[rt][ct], 0, 0, 0);
          acc[rt][ct] = __builtin_amdgcn_mfma_f32_16x16x32_bf16(alo[rt], bh, acc[rt][ct], 0, 0, 0);
        }
      }
    }
    __syncthreads();
  }

  // write per-wave partials (C/D layout: col = l&15, row = (l>>4)*4 + j)
  #pragma unroll
  for (int rt = 0; rt < 2; ++rt)
    #pragma unroll
    for (int ct = 0; ct < 2; ++ct)
      #pragma unroll
      for (int j = 0; j < 4; ++j) {
        int row = rt * 16 + (l >> 4) * 4 + j;
        int cc = ct * 16 + (l & 15);
        part[wv][row][cc] = acc[rt][ct][j];
      }
  __syncthreads();

  // reduce 4 waves + LayerNorm + softmax + masks; 8 rows per pass, 4 passes
  #pragma unroll
  for (int rg = 0; rg < 4; ++rg) {
    int r = rg * 8 + (t >> 5);
    int c = t & 31;
    float d = part[0][r][c] + part[1][r][c] + part[2][r][c] + part[3][r][c];
    float s1 = d;
    for (int m = 1; m < 32; m <<= 1) s1 += __shfl_xor(s1, m);
    float mu = s1 * (1.f / 32.f);
    float dv = d - mu;
    float s2 = dv * dv;
    for (int m = 1; m < 32; m <<= 1) s2 += __shfl_xor(s2, m);
    float var = s2 * (1.f / 32.f);
    float nd = dv * (1.f / sqrtf(var + 1e-5f)) * lnw[c];
    float mx = nd;
    for (int m = 1; m < 32; m <<= 1) mx = fmaxf(mx, __shfl_xor(mx, m));
    float e = expf(nd - mx);
    float se = e;
    for (int m = 1; m < 32; m <<= 1) se += __shfl_xor(se, m);
    bool hit = (e / se) > 0.5f;
    if (hit) atomicOr(&cmask[c], 1);
    int h = hit ? 1 : 0;
    for (int m = 1; m < 32; m <<= 1) h |= __shfl_xor(h, m);
    if (c == 0) {
      size_t row = row0 + r;
      qmask[row] = h;
      if (h) atomicOr(&qtile[row >> 7], 1);
    }
  }
}

// ---------------- K2: expand W to bf16, row-major [OUT_F][IN_F] ----------------
__global__ void k2_expand_w(const float* __restrict__ codebooks,
                            const int* __restrict__ codes,
                            __hip_bfloat16* __restrict__ wb) {
  const int o = blockIdx.x;
  const int tid = threadIdx.x;
  #pragma unroll
  for (int it = 0; it < 2; ++it) {
    int i0 = (it * 256 + tid) * 8;   // 8 contiguous, within one 128-subblock
    int c = i0 >> 7;
    int s = i0 & 127;
    int idx = codes[c * OUT_F + o];
    const float* src = codebooks + ((size_t)(c * 256 + idx)) * 128 + s;
    float4 v0 = *(const float4*)src;
    float4 v1 = *(const float4*)(src + 4);
    union { __hip_bfloat16 b[8]; uint4 q; } u;
    u.b[0] = __float2bfloat16(v0.x); u.b[1] = __float2bfloat16(v0.y);
    u.b[2] = __float2bfloat16(v0.z); u.b[3] = __float2bfloat16(v0.w);
    u.b[4] = __float2bfloat16(v1.x); u.b[5] = __float2bfloat16(v1.y);
    u.b[6] = __float2bfloat16(v1.z); u.b[7] = __float2bfloat16(v1.w);
    *(uint4*)&wb[(size_t)o * IN_F + i0] = u.q;
  }
}

// ---------------- K3: bf16 MFMA GEMM with masked epilogue (m97 structure, unchanged) ----------------
#define BM 128
#define BN 128
#define BKK 64

__global__ __launch_bounds__(256) void k3_gemm(
    const __hip_bfloat16* __restrict__ A,   // xb [8192][4096]
    const __hip_bfloat16* __restrict__ B,   // wb [4096][4096] (row = out col)
    const float* __restrict__ bias,
    const int* __restrict__ qmask, const int* __restrict__ cmask,
    const int* __restrict__ qtile,
    float* __restrict__ out) {
  __shared__ __hip_bfloat16 As[BM][BKK];
  __shared__ __hip_bfloat16 Bs[BN][BKK];
  const int tid = threadIdx.x;
  const int bid = blockIdx.x;
  const int cpx = 2048 >> 3;
  const int swz = (bid & 7) * cpx + (bid >> 3);
  const int bm = swz >> 5;   // 0..63
  const int bn = swz & 31;   // 0..31 (== cluster id)

  if (cmask[bn] == 0 || qtile[bm] == 0) {
    float4 z = make_float4(0.f, 0.f, 0.f, 0.f);
    for (int i = tid; i < BM * BN / 4; i += 256) {
      int rr = i >> 5;
      int cc = (i & 31) << 2;
      *(float4*)&out[((size_t)(bm * BM + rr)) * OUT_F + bn * BN + cc] = z;
    }
    return;
  }

  const int w = tid >> 6, l = tid & 63;
  const int wm = w >> 1, wn = w & 1;
  const int lr = l & 15;
  const int lk = (l >> 4) * 8;

  f32x4 zz = {0.f, 0.f, 0.f, 0.f};
  f32x4 acc[4][4];
  #pragma unroll
  for (int mi = 0; mi < 4; ++mi)
    #pragma unroll
    for (int ni = 0; ni < 4; ++ni) acc[mi][ni] = zz;

  const __hip_bfloat16* Ag = A + ((size_t)bm * BM) * IN_F;
  const __hip_bfloat16* Bg = B + ((size_t)bn * BN) * IN_F;

  for (int k0 = 0; k0 < IN_F; k0 += BKK) {
    #pragma unroll
    for (int i = 0; i < 4; ++i) {
      int chunk = i * 256 + tid;
      int rowa = chunk >> 3;
      int cola = (chunk & 7) * 8;
      gload_lds16(Ag + (size_t)rowa * IN_F + k0 + cola, &As[rowa][cola]);
    }
    #pragma unroll
    for (int i = 0; i < 4; ++i) {
      int chunk = i * 256 + tid;
      int rowb = chunk >> 3;
      int colb = (chunk & 7) * 8;
      gload_lds16(Bg + (size_t)rowb * IN_F + k0 + colb, &Bs[rowb][colb]);
    }
    __syncthreads();
    #pragma unroll
    for (int kk = 0; kk < BKK; kk += 32) {
      bf16x8 af[4], bfr[4];
      #pragma unroll
      for (int mi = 0; mi < 4; ++mi)
        af[mi] = *(const bf16x8*)&As[wm * 64 + mi * 16 + lr][kk + lk];
      #pragma unroll
      for (int ni = 0; ni < 4; ++ni)
        bfr[ni] = *(const bf16x8*)&Bs[wn * 64 + ni * 16 + lr][kk + lk];
      #pragma unroll
      for (int mi = 0; mi < 4; ++mi)
        #pragma unroll
        for (int ni = 0; ni < 4; ++ni)
          acc[mi][ni] = __builtin_amdgcn_mfma_f32_16x16x32_bf16(
              af[mi], bfr[ni], acc[mi][ni], 0, 0, 0);
    }
    __syncthreads();
  }

  const int mb = bm * BM + wm * 64;
  const int nb = bn * BN + wn * 64;
  #pragma unroll
  for (int mi = 0; mi < 4; ++mi) {
    #pragma unroll
    for (int j = 0; j < 4; ++j) {
      int rrow = mb + mi * 16 + (l >> 4) * 4 + j;
      float qm = qmask[rrow] ? 1.f : 0.f;
      #pragma unroll
      for (int ni = 0; ni < 4; ++ni) {
        int ccol = nb + ni * 16 + lr;
        out[(size_t)rrow * OUT_F + ccol] = (acc[mi][ni][j] + bias[ccol]) * qm;
      }
    }
  }
}

extern "C" void kernel_launch(void* const* d_in, const int* in_sizes, int n_in,
                              void* d_out, int out_size, void* d_ws, size_t ws_size,
                              hipStream_t stream) {
  const float* x = (const float*)d_in[0];
  const float* codebooks = (const float*)d_in[1];
  const float* bias = (const float*)d_in[2];
  const float* lnw = (const float*)d_in[3];
  const int* codes = (const int*)d_in[4];       // [32][4096]
  const int* centroids = (const int*)d_in[5];   // [32][32]
  float* out = (float*)d_out;

  char* ws = (char*)d_ws;
  int* cmask = (int*)(ws + OFF_CMASK);
  int* qtile = (int*)(ws + OFF_QTILE);
  int* qmask = (int*)(ws + OFF_QMASK);
  uint4* whi = (uint4*)(ws + OFF_WHI);
  uint4* wlo = (uint4*)(ws + OFF_WLO);
  __hip_bfloat16* xb = (__hip_bfloat16*)(ws + OFF_XB);
  __hip_bfloat16* wb = (__hip_bfloat16*)(ws + OFF_WB);

  hipLaunchKernelGGL(k0b_fragw, dim3(64), dim3(256), 0, stream,
                     codebooks, centroids, whi, wlo, cmask, qtile);
  hipLaunchKernelGGL(k1_dots, dim3(256), dim3(256), 0, stream,
                     x, whi, wlo, lnw, xb, qmask, cmask, qtile);
  hipLaunchKernelGGL(k2_expand_w, dim3(4096), dim3(256), 0, stream,
                     codebooks, codes, wb);
  hipLaunchKernelGGL(k3_gemm, dim3(2048), dim3(256), 0, stream,
                     xb, wb, bias, qmask, cmask, qtile, out);
}

// Round 6
// 532.717 us; speedup vs baseline: 2.0307x; 1.2770x over previous
//
#include <hip/hip_runtime.h>
#include <hip/hip_bf16.h>
#include <stdint.h>

#define IN_F 4096
#define OUT_F 4096
#define NCLUST 32
#define MROWS 8192

typedef __attribute__((ext_vector_type(8))) short bf16x8;
typedef __attribute__((ext_vector_type(4))) float f32x4;

// ---------------- workspace layout (bytes) ----------------
#define OFF_CMASK ((size_t)0)                 // 32 * 4
#define OFF_QTILE ((size_t)256)               // 64 * 4
#define OFF_QMASK ((size_t)1024)              // 8192 * 4
#define OFF_WHI   ((size_t)65536)             // 256 KB
#define OFF_WLO   ((size_t)(65536 + 262144))  // 256 KB
#define OFF_XB    ((size_t)1 << 20)           // 64 MB
#define OFF_WB    (((size_t)1 << 20) + (size_t)MROWS * IN_F * 2)  // 32 MB

__device__ __forceinline__ void gload_lds16(const void* g, void* l) {
  __builtin_amdgcn_global_load_lds(
      (const __attribute__((address_space(1))) void*)g,
      (__attribute__((address_space(3))) void*)l, 16, 0, 0);
}

// ---------------- K0b: precompute cw B-fragments (hi/lo bf16) + zero masks ----------------
__global__ void k0b_fragw(const float* __restrict__ codebooks,
                          const int* __restrict__ centroids,
                          uint4* __restrict__ whi, uint4* __restrict__ wlo,
                          int* __restrict__ cmask, int* __restrict__ qtile) {
  int gid = blockIdx.x * 256 + threadIdx.x;   // [0, 16384)
  int l = gid & 63;
  int ct = (gid >> 6) & 1;
  int ks = gid >> 7;                           // 0..127 (k-step of 32)
  int c = ct * 16 + (l & 15);                  // cluster 0..31
  int k0 = ks * 32 + 8 * (l >> 4);             // 8-aligned
  int sub = k0 >> 7;
  int off = k0 & 127;
  int idx = centroids[sub * 32 + c];
  const float* src = codebooks + ((size_t)(sub * 256 + idx)) * 128 + off;
  float4 v0 = *(const float4*)src;
  float4 v1 = *(const float4*)(src + 4);
  float f[8] = {v0.x, v0.y, v0.z, v0.w, v1.x, v1.y, v1.z, v1.w};
  union { __hip_bfloat16 b[8]; uint4 q; } uh, ul;
  #pragma unroll
  for (int i = 0; i < 8; ++i) {
    __hip_bfloat16 h = __float2bfloat16(f[i]);
    uh.b[i] = h;
    ul.b[i] = __float2bfloat16(f[i] - __bfloat162float(h));
  }
  whi[gid] = uh.q;
  wlo[gid] = ul.q;
  if (gid < 32) cmask[gid] = 0;
  else if (gid < 96) qtile[gid - 32] = 0;
}

// ---------------- K1: fused x->bf16 convert + MFMA routing dots + LN + softmax + masks ----------------
__global__ __launch_bounds__(256) void k1_dots(
    const float* __restrict__ x,
    const uint4* __restrict__ whi4, const uint4* __restrict__ wlo4,
    const float* __restrict__ lnw,
    __hip_bfloat16* __restrict__ xb,
    int* __restrict__ qmask, int* __restrict__ cmask, int* __restrict__ qtile) {
  __shared__ __align__(16) float xsf[32 * 256];
  __shared__ float part[4][32][32];
  const int t = threadIdx.x;
  const int wv = t >> 6;
  const int l = t & 63;
  const size_t row0 = (size_t)blockIdx.x * 32;
  const float* xg = x + row0 * IN_F;
  const bf16x8* whif = (const bf16x8*)whi4;
  const bf16x8* wlof = (const bf16x8*)wlo4;

  f32x4 zz = {0.f, 0.f, 0.f, 0.f};
  f32x4 acc[2][2];
  acc[0][0] = zz; acc[0][1] = zz; acc[1][0] = zz; acc[1][1] = zz;

  const int col = (t & 63) * 4;
  float4 reg[8];
  #pragma unroll
  for (int j = 0; j < 8; ++j)
    reg[j] = *(const float4*)&xg[(size_t)(4 * j + wv) * IN_F + col];

  for (int ch = 0; ch < 16; ++ch) {
    #pragma unroll
    for (int j = 0; j < 8; ++j) {
      int row = 4 * j + wv;
      int sw = (row & 7) << 2;
      *(float4*)&xsf[row * 256 + (col ^ sw)] = reg[j];
      union { __hip_bfloat16 b[4]; uint2 q; } u;
      u.b[0] = __float2bfloat16(reg[j].x);
      u.b[1] = __float2bfloat16(reg[j].y);
      u.b[2] = __float2bfloat16(reg[j].z);
      u.b[3] = __float2bfloat16(reg[j].w);
      *(uint2*)&xb[(row0 + row) * IN_F + ch * 256 + col] = u.q;
    }
    if (ch + 1 < 16) {
      #pragma unroll
      for (int j = 0; j < 8; ++j)
        reg[j] = *(const float4*)&xg[(size_t)(4 * j + wv) * IN_F + (ch + 1) * 256 + col];
    }
    __syncthreads();
    #pragma unroll
    for (int s = 0; s < 2; ++s) {
      int kk = wv * 64 + s * 32 + 8 * (l >> 4);
      int gk = ch * 8 + wv * 2 + s;
      bf16x8 ahi[2], alo[2];
      #pragma unroll
      for (int rt = 0; rt < 2; ++rt) {
        int row = rt * 16 + (l & 15);
        int sw = (row & 7) << 2;
        float4 f0 = *(const float4*)&xsf[row * 256 + (kk ^ sw)];
        float4 f1 = *(const float4*)&xsf[row * 256 + ((kk ^ sw) ^ 4)];
        float f[8] = {f0.x, f0.y, f0.z, f0.w, f1.x, f1.y, f1.z, f1.w};
        union { __hip_bfloat16 b[8]; bf16x8 v; } uh, ul;
        #pragma unroll
        for (int i = 0; i < 8; ++i) {
          __hip_bfloat16 h = __float2bfloat16(f[i]);
          uh.b[i] = h;
          ul.b[i] = __float2bfloat16(f[i] - __bfloat162float(h));
        }
        ahi[rt] = uh.v; alo[rt] = ul.v;
      }
      #pragma unroll
      for (int ct = 0; ct < 2; ++ct) {
        bf16x8 bh = whif[(gk * 2 + ct) * 64 + l];
        bf16x8 bl = wlof[(gk * 2 + ct) * 64 + l];
        #pragma unroll
        for (int rt = 0; rt < 2; ++rt) {
          acc[rt][ct] = __builtin_amdgcn_mfma_f32_16x16x32_bf16(ahi[rt], bh, acc[rt][ct], 0, 0, 0);
          acc[rt][ct] = __builtin_amdgcn_mfma_f32_16x16x32_bf16(ahi[rt], bl, acc[rt][ct], 0, 0, 0);
          acc[rt][ct] = __builtin_amdgcn_mfma_f32_16x16x32_bf16(alo[rt], bh, acc[rt][ct], 0, 0, 0);
        }
      }
    }
    __syncthreads();
  }

  #pragma unroll
  for (int rt = 0; rt < 2; ++rt)
    #pragma unroll
    for (int ct = 0; ct < 2; ++ct)
      #pragma unroll
      for (int j = 0; j < 4; ++j) {
        int row = rt * 16 + (l >> 4) * 4 + j;
        int cc = ct * 16 + (l & 15);
        part[wv][row][cc] = acc[rt][ct][j];
      }
  __syncthreads();

  #pragma unroll
  for (int rg = 0; rg < 4; ++rg) {
    int r = rg * 8 + (t >> 5);
    int c = t & 31;
    float d = part[0][r][c] + part[1][r][c] + part[2][r][c] + part[3][r][c];
    float s1 = d;
    for (int m = 1; m < 32; m <<= 1) s1 += __shfl_xor(s1, m);
    float mu = s1 * (1.f / 32.f);
    float dv = d - mu;
    float s2 = dv * dv;
    for (int m = 1; m < 32; m <<= 1) s2 += __shfl_xor(s2, m);
    float var = s2 * (1.f / 32.f);
    float nd = dv * (1.f / sqrtf(var + 1e-5f)) * lnw[c];
    float mx = nd;
    for (int m = 1; m < 32; m <<= 1) mx = fmaxf(mx, __shfl_xor(mx, m));
    float e = expf(nd - mx);
    float se = e;
    for (int m = 1; m < 32; m <<= 1) se += __shfl_xor(se, m);
    bool hit = (e / se) > 0.5f;
    if (hit) atomicOr(&cmask[c], 1);
    int h = hit ? 1 : 0;
    for (int m = 1; m < 32; m <<= 1) h |= __shfl_xor(h, m);
    if (c == 0) {
      size_t row = row0 + r;
      qmask[row] = h;
      if (h) atomicOr(&qtile[row >> 7], 1);
    }
  }
}

// ---------------- K2: expand W to bf16, row-major [OUT_F][IN_F] ----------------
__global__ void k2_expand_w(const float* __restrict__ codebooks,
                            const int* __restrict__ codes,
                            __hip_bfloat16* __restrict__ wb) {
  const int o = blockIdx.x;
  const int tid = threadIdx.x;
  #pragma unroll
  for (int it = 0; it < 2; ++it) {
    int i0 = (it * 256 + tid) * 8;
    int c = i0 >> 7;
    int s = i0 & 127;
    int idx = codes[c * OUT_F + o];
    const float* src = codebooks + ((size_t)(c * 256 + idx)) * 128 + s;
    float4 v0 = *(const float4*)src;
    float4 v1 = *(const float4*)(src + 4);
    union { __hip_bfloat16 b[8]; uint4 q; } u;
    u.b[0] = __float2bfloat16(v0.x); u.b[1] = __float2bfloat16(v0.y);
    u.b[2] = __float2bfloat16(v0.z); u.b[3] = __float2bfloat16(v0.w);
    u.b[4] = __float2bfloat16(v1.x); u.b[5] = __float2bfloat16(v1.y);
    u.b[6] = __float2bfloat16(v1.z); u.b[7] = __float2bfloat16(v1.w);
    *(uint4*)&wb[(size_t)o * IN_F + i0] = u.q;
  }
}

// ---------------- K3: 256x256 8-phase bf16 MFMA GEMM (T2+T3+T4+T5) ----------------
// 512 thr = 8 waves (wm = w>>2 in {0,1}, wn = w&3 in {0..3}); per-wave out 128x64
// spread over both halves: rows {wm*64+[0,64)} U {128+wm*64+[0,64)}, cols similarly.
// Phase = quadrant (MH,NH): 12 ds_read_b128 + stage + bar + lgkm0 + 16 MFMA + bar.
// LDS: A[2buf][256][128B] then B[2buf][256][128B] = 128 KB. Swizzle: chunk ^= row&7,
// applied on global source (stage) and on ds_read (rule 21 both-sides involution).

__global__ __launch_bounds__(512, 2) void k3_gemm(
    const __hip_bfloat16* __restrict__ A,   // xb [8192][4096]
    const __hip_bfloat16* __restrict__ B,   // wb [4096][4096] (row = out col)
    const float* __restrict__ bias,
    const int* __restrict__ qmask, const int* __restrict__ cmask,
    const int* __restrict__ qtile,
    float* __restrict__ out) {
  __shared__ char smem[131072];
  const int tid = threadIdx.x;
  const int bid = blockIdx.x;
  // XCD-aware bijective swizzle: 512 blocks, 512 % 8 == 0
  const int swz = (bid & 7) * 64 + (bid >> 3);
  const int bm = swz >> 4;   // 0..31
  const int bn = swz & 15;   // 0..15
  const int m0 = bm * 256;
  const int n0 = bn * 256;

  const int cmA = cmask[bn * 2], cmB = cmask[bn * 2 + 1];
  if ((qtile[bm * 2] | qtile[bm * 2 + 1]) == 0 || (cmA | cmB) == 0) {
    float4 z = make_float4(0.f, 0.f, 0.f, 0.f);
    for (int i = tid; i < 256 * 64; i += 512) {
      int rr = i >> 6;
      int cc = (i & 63) << 2;
      *(float4*)&out[((size_t)(m0 + rr)) * OUT_F + n0 + cc] = z;
    }
    return;
  }

  const int w = tid >> 6;        // wave 0..7
  const int l = tid & 63;
  const int wm = w >> 2;         // 0..1
  const int wn = w & 3;          // 0..3
  const int wmo = wm * 64;
  const int wno = wn * 32;
  const int lr = l & 15;
  const int g = l >> 4;          // 0..3
  const int lb = l & 7;
  const int r8 = l >> 3;         // 0..7
  const int csw = ((l & 7) ^ r8) << 4;  // pre-swizzled global 16B-chunk offset
  const size_t rowb = (size_t)IN_F * 2;

  const char* Asrc = (const char*)A + (size_t)(m0 + w * 8 + r8) * rowb + csw;
  const char* Bsrc = (const char*)B + (size_t)(n0 + w * 8 + r8) * rowb + csw;

// stage one 64-row chunk (j) of half h of K-tile t into buf b (per-thread: 1 load)
#define STAGE_A(b, h, j, t) gload_lds16( \
    Asrc + (size_t)((h)*128 + (j)*64) * rowb + (size_t)(t) * 128, \
    smem + (b)*32768 + ((h)*128 + (j)*64 + w*8) * 128)
#define STAGE_B(b, h, j, t) gload_lds16( \
    Bsrc + (size_t)((h)*128 + (j)*64) * rowb + (size_t)(t) * 128, \
    smem + 65536 + (b)*32768 + ((h)*128 + (j)*64 + w*8) * 128)

#define VM4 asm volatile("s_waitcnt vmcnt(4)" ::: "memory")
#define VMN

#define PHASE(MH, NH, BUF, STAGES, VMW) do { \
    bf16x8 af[4][2], bfq[2][2]; \
    const char* sAb = smem + (BUF) * 32768; \
    const char* sBb = smem + 65536 + (BUF) * 32768; \
    _Pragma("unroll") \
    for (int mi = 0; mi < 4; ++mi) { \
      int R = (MH)*128 + wmo + mi*16 + lr; \
      int c0 = ((g ^ lb) << 4); \
      af[mi][0] = *(const bf16x8*)(sAb + R*128 + c0); \
      af[mi][1] = *(const bf16x8*)(sAb + R*128 + (((4 + g) ^ lb) << 4)); \
    } \
    _Pragma("unroll") \
    for (int ni = 0; ni < 2; ++ni) { \
      int R = (NH)*128 + wno + ni*16 + lr; \
      bfq[ni][0] = *(const bf16x8*)(sBb + R*128 + ((g ^ lb) << 4)); \
      bfq[ni][1] = *(const bf16x8*)(sBb + R*128 + (((4 + g) ^ lb) << 4)); \
    } \
    STAGES; \
    VMW; \
    __builtin_amdgcn_sched_barrier(0); \
    __builtin_amdgcn_s_barrier(); \
    asm volatile("s_waitcnt lgkmcnt(0)" ::: "memory"); \
    __builtin_amdgcn_sched_barrier(0); \
    __builtin_amdgcn_s_setprio(1); \
    _Pragma("unroll") \
    for (int mi = 0; mi < 4; ++mi) \
      _Pragma("unroll") \
      for (int ni = 0; ni < 2; ++ni) { \
        acc[MH][NH][mi][ni] = __builtin_amdgcn_mfma_f32_16x16x32_bf16( \
            af[mi][0], bfq[ni][0], acc[MH][NH][mi][ni], 0, 0, 0); \
        acc[MH][NH][mi][ni] = __builtin_amdgcn_mfma_f32_16x16x32_bf16( \
            af[mi][1], bfq[ni][1], acc[MH][NH][mi][ni], 0, 0, 0); \
      } \
    __builtin_amdgcn_s_setprio(0); \
    __builtin_amdgcn_s_barrier(); \
  } while (0)

  f32x4 zz = {0.f, 0.f, 0.f, 0.f};
  f32x4 acc[2][2][4][2];
  #pragma unroll
  for (int a = 0; a < 2; ++a)
    #pragma unroll
    for (int b = 0; b < 2; ++b)
      #pragma unroll
      for (int c = 0; c < 4; ++c)
        #pragma unroll
        for (int d = 0; d < 2; ++d) acc[a][b][c][d] = zz;

  // prologue: tile0 full -> buf0 (8 loads), tile1 Ah0+Bh0 -> buf1 (4 loads)
  STAGE_A(0, 0, 0, 0); STAGE_A(0, 0, 1, 0);
  STAGE_B(0, 0, 0, 0); STAGE_B(0, 0, 1, 0);
  STAGE_A(0, 1, 0, 0); STAGE_A(0, 1, 1, 0);
  STAGE_B(0, 1, 0, 0); STAGE_B(0, 1, 1, 0);
  STAGE_A(1, 0, 0, 1); STAGE_A(1, 0, 1, 1);
  STAGE_B(1, 0, 0, 1); STAGE_B(1, 0, 1, 1);
  asm volatile("s_waitcnt vmcnt(4)" ::: "memory");   // tile0 landed
  __builtin_amdgcn_s_barrier();

  // steady state: iter i computes tiles 2i (buf0, p1-4) and 2i+1 (buf1, p5-8).
  // stage slots: p1: t1.Ah1+Bh1->buf1 | p3: t2.Ah0->buf0 | p4: t2.Bh0->buf0 (VM4)
  //              p5: t2.Ah1+Bh1->buf0 | p7: t3.Ah0->buf1 | p8: t3.Bh0->buf1 (VM4)
  // last iter: t2,t3 wrap to tiles 0,1 (harmless dead stores into spent buffers).
  for (int i = 0; i < 32; ++i) {
    const int t1 = 2 * i + 1;
    const int t2 = (2 * i + 2) & 63;
    const int t3 = (2 * i + 3) & 63;
    PHASE(0, 0, 0, { STAGE_A(1,1,0,t1); STAGE_A(1,1,1,t1); STAGE_B(1,1,0,t1); STAGE_B(1,1,1,t1); }, VMN);
    PHASE(0, 1, 0, {}, VMN);
    PHASE(1, 0, 0, { STAGE_A(0,0,0,t2); STAGE_A(0,0,1,t2); }, VMN);
    PHASE(1, 1, 0, { STAGE_B(0,0,0,t2); STAGE_B(0,0,1,t2); }, VM4);
    PHASE(0, 0, 1, { STAGE_A(0,1,0,t2); STAGE_A(0,1,1,t2); STAGE_B(0,1,0,t2); STAGE_B(0,1,1,t2); }, VMN);
    PHASE(0, 1, 1, {}, VMN);
    PHASE(1, 0, 1, { STAGE_A(1,0,0,t3); STAGE_A(1,0,1,t3); }, VMN);
    PHASE(1, 1, 1, { STAGE_B(1,0,0,t3); STAGE_B(1,0,1,t3); }, VM4);
  }

  // drain outstanding gload_lds before LDS goes out of scope / epilogue
  asm volatile("s_waitcnt vmcnt(0)" ::: "memory");

  // epilogue: +bias, qmask per row, cmask per 128-col cluster
  const int g4 = g * 4;
  #pragma unroll
  for (int MH = 0; MH < 2; ++MH) {
    #pragma unroll
    for (int mi = 0; mi < 4; ++mi) {
      #pragma unroll
      for (int j = 0; j < 4; ++j) {
        int row = m0 + MH * 128 + wmo + mi * 16 + g4 + j;
        float qm = qmask[row] ? 1.f : 0.f;
        float fA = qm * (cmA ? 1.f : 0.f);
        float fB = qm * (cmB ? 1.f : 0.f);
        #pragma unroll
        for (int NH = 0; NH < 2; ++NH) {
          float fc = NH ? fB : fA;
          #pragma unroll
          for (int ni = 0; ni < 2; ++ni) {
            int col = n0 + NH * 128 + wno + ni * 16 + lr;
            out[(size_t)row * OUT_F + col] =
                (acc[MH][NH][mi][ni][j] + bias[col]) * fc;
          }
        }
      }
    }
  }
#undef PHASE
#undef STAGE_A
#undef STAGE_B
#undef VM4
#undef VMN
}

extern "C" void kernel_launch(void* const* d_in, const int* in_sizes, int n_in,
                              void* d_out, int out_size, void* d_ws, size_t ws_size,
                              hipStream_t stream) {
  const float* x = (const float*)d_in[0];
  const float* codebooks = (const float*)d_in[1];
  const float* bias = (const float*)d_in[2];
  const float* lnw = (const float*)d_in[3];
  const int* codes = (const int*)d_in[4];       // [32][4096]
  const int* centroids = (const int*)d_in[5];   // [32][32]
  float* out = (float*)d_out;

  char* ws = (char*)d_ws;
  int* cmask = (int*)(ws + OFF_CMASK);
  int* qtile = (int*)(ws + OFF_QTILE);
  int* qmask = (int*)(ws + OFF_QMASK);
  uint4* whi = (uint4*)(ws + OFF_WHI);
  uint4* wlo = (uint4*)(ws + OFF_WLO);
  __hip_bfloat16* xb = (__hip_bfloat16*)(ws + OFF_XB);
  __hip_bfloat16* wb = (__hip_bfloat16*)(ws + OFF_WB);

  hipLaunchKernelGGL(k0b_fragw, dim3(64), dim3(256), 0, stream,
                     codebooks, centroids, whi, wlo, cmask, qtile);
  hipLaunchKernelGGL(k1_dots, dim3(256), dim3(256), 0, stream,
                     x, whi, wlo, lnw, xb, qmask, cmask, qtile);
  hipLaunchKernelGGL(k2_expand_w, dim3(4096), dim3(256), 0, stream,
                     codebooks, codes, wb);
  hipLaunchKernelGGL(k3_gemm, dim3(512), dim3(512), 0, stream,
                     xb, wb, bias, qmask, cmask, qtile, out);
}

// Round 7
// 531.176 us; speedup vs baseline: 2.0365x; 1.0029x over previous
//
#include <hip/hip_runtime.h>
#include <hip/hip_bf16.h>
#include <stdint.h>

#define IN_F 4096
#define OUT_F 4096
#define NCLUST 32
#define MROWS 8192

typedef __attribute__((ext_vector_type(8))) short bf16x8;
typedef __attribute__((ext_vector_type(4))) float f32x4;

// ---------------- workspace layout (bytes) ----------------
#define OFF_CMASK ((size_t)0)                 // 32 * 4
#define OFF_QTILE ((size_t)256)               // 64 * 4
#define OFF_QMASK ((size_t)1024)              // 8192 * 4
#define OFF_WHI   ((size_t)65536)             // 256 KB
#define OFF_WLO   ((size_t)(65536 + 262144))  // 256 KB
#define OFF_XB    ((size_t)1 << 20)           // 64 MB
#define OFF_WB    (((size_t)1 << 20) + (size_t)MROWS * IN_F * 2)  // 32 MB

__device__ __forceinline__ void gload_lds16(const void* g, void* l) {
  __builtin_amdgcn_global_load_lds(
      (const __attribute__((address_space(1))) void*)g,
      (__attribute__((address_space(3))) void*)l, 16, 0, 0);
}

// ---------------- K0b: precompute cw B-fragments (hi/lo bf16) + zero masks ----------------
__global__ void k0b_fragw(const float* __restrict__ codebooks,
                          const int* __restrict__ centroids,
                          uint4* __restrict__ whi, uint4* __restrict__ wlo,
                          int* __restrict__ cmask, int* __restrict__ qtile) {
  int gid = blockIdx.x * 256 + threadIdx.x;   // [0, 16384)
  int l = gid & 63;
  int ct = (gid >> 6) & 1;
  int ks = gid >> 7;                           // 0..127 (k-step of 32)
  int c = ct * 16 + (l & 15);                  // cluster 0..31
  int k0 = ks * 32 + 8 * (l >> 4);             // 8-aligned
  int sub = k0 >> 7;
  int off = k0 & 127;
  int idx = centroids[sub * 32 + c];
  const float* src = codebooks + ((size_t)(sub * 256 + idx)) * 128 + off;
  float4 v0 = *(const float4*)src;
  float4 v1 = *(const float4*)(src + 4);
  float f[8] = {v0.x, v0.y, v0.z, v0.w, v1.x, v1.y, v1.z, v1.w};
  union { __hip_bfloat16 b[8]; uint4 q; } uh, ul;
  #pragma unroll
  for (int i = 0; i < 8; ++i) {
    __hip_bfloat16 h = __float2bfloat16(f[i]);
    uh.b[i] = h;
    ul.b[i] = __float2bfloat16(f[i] - __bfloat162float(h));
  }
  whi[gid] = uh.q;
  wlo[gid] = ul.q;
  if (gid < 32) cmask[gid] = 0;
  else if (gid < 96) qtile[gid - 32] = 0;
}

// ---------------- K1a: pure streaming convert x -> bf16 xb ----------------
__global__ __launch_bounds__(256) void k1a_convert(const float* __restrict__ x,
                                                   __hip_bfloat16* __restrict__ xb) {
  size_t i = ((size_t)blockIdx.x * 256 + threadIdx.x) * 8;
  const size_t stride = (size_t)gridDim.x * 256 * 8;
  const size_t total = (size_t)MROWS * IN_F;
  for (; i < total; i += stride) {
    float4 v0 = *(const float4*)&x[i];
    float4 v1 = *(const float4*)&x[i + 4];
    union { __hip_bfloat16 b[8]; uint4 q; } u;
    u.b[0] = __float2bfloat16(v0.x); u.b[1] = __float2bfloat16(v0.y);
    u.b[2] = __float2bfloat16(v0.z); u.b[3] = __float2bfloat16(v0.w);
    u.b[4] = __float2bfloat16(v1.x); u.b[5] = __float2bfloat16(v1.y);
    u.b[6] = __float2bfloat16(v1.z); u.b[7] = __float2bfloat16(v1.w);
    *(uint4*)&xb[i] = u.q;
  }
}

// ---------------- K1b: MFMA routing dots (fp32 x, 3-term hi/lo split) + LN + softmax + masks ----------------
// 256 blocks x 512 thr (8 waves); block owns 32 rows; wave wv owns K-slice [wv*512, wv*512+512).
// No in-loop barriers; A-fragments gathered straight from global fp32 x into registers.
__global__ __launch_bounds__(512) void k1b_dots(
    const float* __restrict__ x,
    const uint4* __restrict__ whi4, const uint4* __restrict__ wlo4,
    const float* __restrict__ lnw,
    int* __restrict__ qmask, int* __restrict__ cmask, int* __restrict__ qtile) {
  __shared__ float part[8][32][32];
  const int t = threadIdx.x;
  const int wv = t >> 6;          // wave 0..7
  const int l = t & 63;
  const size_t row0 = (size_t)blockIdx.x * 32;
  const bf16x8* whif = (const bf16x8*)whi4;
  const bf16x8* wlof = (const bf16x8*)wlo4;

  f32x4 zz = {0.f, 0.f, 0.f, 0.f};
  f32x4 acc[2][2];
  acc[0][0] = zz; acc[0][1] = zz; acc[1][0] = zz; acc[1][1] = zz;

  const int lrow = l & 15;
  const int kgrp = (l >> 4) * 8;   // 0,8,16,24

  for (int ks = 0; ks < 16; ++ks) {
    const int gk = wv * 16 + ks;          // global k-step 0..127
    const int kb = gk * 32 + kgrp;        // fp32 elem index within row
    bf16x8 ahi[2], alo[2];
    #pragma unroll
    for (int rt = 0; rt < 2; ++rt) {
      const float* src = &x[(row0 + rt * 16 + lrow) * IN_F + kb];
      float4 f0 = *(const float4*)src;
      float4 f1 = *(const float4*)(src + 4);
      float f[8] = {f0.x, f0.y, f0.z, f0.w, f1.x, f1.y, f1.z, f1.w};
      union { __hip_bfloat16 b[8]; bf16x8 v; } uh, ul;
      #pragma unroll
      for (int i = 0; i < 8; ++i) {
        __hip_bfloat16 h = __float2bfloat16(f[i]);
        uh.b[i] = h;
        ul.b[i] = __float2bfloat16(f[i] - __bfloat162float(h));
      }
      ahi[rt] = uh.v; alo[rt] = ul.v;
    }
    #pragma unroll
    for (int ct = 0; ct < 2; ++ct) {
      bf16x8 bh = whif[(gk * 2 + ct) * 64 + l];
      bf16x8 bl = wlof[(gk * 2 + ct) * 64 + l];
      #pragma unroll
      for (int rt = 0; rt < 2; ++rt) {
        acc[rt][ct] = __builtin_amdgcn_mfma_f32_16x16x32_bf16(ahi[rt], bh, acc[rt][ct], 0, 0, 0);
        acc[rt][ct] = __builtin_amdgcn_mfma_f32_16x16x32_bf16(ahi[rt], bl, acc[rt][ct], 0, 0, 0);
        acc[rt][ct] = __builtin_amdgcn_mfma_f32_16x16x32_bf16(alo[rt], bh, acc[rt][ct], 0, 0, 0);
      }
    }
  }

  // per-wave partials (C/D layout: col = l&15, row = (l>>4)*4 + j)
  #pragma unroll
  for (int rt = 0; rt < 2; ++rt)
    #pragma unroll
    for (int ct = 0; ct < 2; ++ct)
      #pragma unroll
      for (int j = 0; j < 4; ++j) {
        int row = rt * 16 + (l >> 4) * 4 + j;
        int cc = ct * 16 + (l & 15);
        part[wv][row][cc] = acc[rt][ct][j];
      }
  __syncthreads();

  // reduce 8 waves + LayerNorm + softmax + masks; 16 rows per pass, 2 passes
  #pragma unroll
  for (int pass = 0; pass < 2; ++pass) {
    int r = pass * 16 + (t >> 5);
    int c = t & 31;
    float d = 0.f;
    #pragma unroll
    for (int w8 = 0; w8 < 8; ++w8) d += part[w8][r][c];
    float s1 = d;
    for (int m = 1; m < 32; m <<= 1) s1 += __shfl_xor(s1, m);
    float mu = s1 * (1.f / 32.f);
    float dv = d - mu;
    float s2 = dv * dv;
    for (int m = 1; m < 32; m <<= 1) s2 += __shfl_xor(s2, m);
    float var = s2 * (1.f / 32.f);
    float nd = dv * (1.f / sqrtf(var + 1e-5f)) * lnw[c];
    float mx = nd;
    for (int m = 1; m < 32; m <<= 1) mx = fmaxf(mx, __shfl_xor(mx, m));
    float e = expf(nd - mx);
    float se = e;
    for (int m = 1; m < 32; m <<= 1) se += __shfl_xor(se, m);
    bool hit = (e / se) > 0.5f;
    if (hit) atomicOr(&cmask[c], 1);
    int h = hit ? 1 : 0;
    for (int m = 1; m < 32; m <<= 1) h |= __shfl_xor(h, m);
    if (c == 0) {
      size_t row = row0 + r;
      qmask[row] = h;
      if (h) atomicOr(&qtile[row >> 7], 1);
    }
  }
}

// ---------------- K2: expand W to bf16, row-major [OUT_F][IN_F] ----------------
__global__ void k2_expand_w(const float* __restrict__ codebooks,
                            const int* __restrict__ codes,
                            __hip_bfloat16* __restrict__ wb) {
  const int o = blockIdx.x;
  const int tid = threadIdx.x;
  #pragma unroll
  for (int it = 0; it < 2; ++it) {
    int i0 = (it * 256 + tid) * 8;
    int c = i0 >> 7;
    int s = i0 & 127;
    int idx = codes[c * OUT_F + o];
    const float* src = codebooks + ((size_t)(c * 256 + idx)) * 128 + s;
    float4 v0 = *(const float4*)src;
    float4 v1 = *(const float4*)(src + 4);
    union { __hip_bfloat16 b[8]; uint4 q; } u;
    u.b[0] = __float2bfloat16(v0.x); u.b[1] = __float2bfloat16(v0.y);
    u.b[2] = __float2bfloat16(v0.z); u.b[3] = __float2bfloat16(v0.w);
    u.b[4] = __float2bfloat16(v1.x); u.b[5] = __float2bfloat16(v1.y);
    u.b[6] = __float2bfloat16(v1.z); u.b[7] = __float2bfloat16(v1.w);
    *(uint4*)&wb[(size_t)o * IN_F + i0] = u.q;
  }
}

// ---------------- K3: 256x256 8-phase bf16 MFMA GEMM (T2+T3+T4+T5) — unchanged ----------------
__global__ __launch_bounds__(512, 2) void k3_gemm(
    const __hip_bfloat16* __restrict__ A,   // xb [8192][4096]
    const __hip_bfloat16* __restrict__ B,   // wb [4096][4096] (row = out col)
    const float* __restrict__ bias,
    const int* __restrict__ qmask, const int* __restrict__ cmask,
    const int* __restrict__ qtile,
    float* __restrict__ out) {
  __shared__ char smem[131072];
  const int tid = threadIdx.x;
  const int bid = blockIdx.x;
  // XCD-aware bijective swizzle: 512 blocks, 512 % 8 == 0
  const int swz = (bid & 7) * 64 + (bid >> 3);
  const int bm = swz >> 4;   // 0..31
  const int bn = swz & 15;   // 0..15
  const int m0 = bm * 256;
  const int n0 = bn * 256;

  const int cmA = cmask[bn * 2], cmB = cmask[bn * 2 + 1];
  if ((qtile[bm * 2] | qtile[bm * 2 + 1]) == 0 || (cmA | cmB) == 0) {
    float4 z = make_float4(0.f, 0.f, 0.f, 0.f);
    for (int i = tid; i < 256 * 64; i += 512) {
      int rr = i >> 6;
      int cc = (i & 63) << 2;
      *(float4*)&out[((size_t)(m0 + rr)) * OUT_F + n0 + cc] = z;
    }
    return;
  }

  const int w = tid >> 6;        // wave 0..7
  const int l = tid & 63;
  const int wm = w >> 2;         // 0..1
  const int wn = w & 3;          // 0..3
  const int wmo = wm * 64;
  const int wno = wn * 32;
  const int lr = l & 15;
  const int g = l >> 4;          // 0..3
  const int lb = l & 7;
  const int r8 = l >> 3;         // 0..7
  const int csw = ((l & 7) ^ r8) << 4;  // pre-swizzled global 16B-chunk offset
  const size_t rowb = (size_t)IN_F * 2;

  const char* Asrc = (const char*)A + (size_t)(m0 + w * 8 + r8) * rowb + csw;
  const char* Bsrc = (const char*)B + (size_t)(n0 + w * 8 + r8) * rowb + csw;

#define STAGE_A(b, h, j, t) gload_lds16( \
    Asrc + (size_t)((h)*128 + (j)*64) * rowb + (size_t)(t) * 128, \
    smem + (b)*32768 + ((h)*128 + (j)*64 + w*8) * 128)
#define STAGE_B(b, h, j, t) gload_lds16( \
    Bsrc + (size_t)((h)*128 + (j)*64) * rowb + (size_t)(t) * 128, \
    smem + 65536 + (b)*32768 + ((h)*128 + (j)*64 + w*8) * 128)

#define VM4 asm volatile("s_waitcnt vmcnt(4)" ::: "memory")
#define VMN

#define PHASE(MH, NH, BUF, STAGES, VMW) do { \
    bf16x8 af[4][2], bfq[2][2]; \
    const char* sAb = smem + (BUF) * 32768; \
    const char* sBb = smem + 65536 + (BUF) * 32768; \
    _Pragma("unroll") \
    for (int mi = 0; mi < 4; ++mi) { \
      int R = (MH)*128 + wmo + mi*16 + lr; \
      int c0 = ((g ^ lb) << 4); \
      af[mi][0] = *(const bf16x8*)(sAb + R*128 + c0); \
      af[mi][1] = *(const bf16x8*)(sAb + R*128 + (((4 + g) ^ lb) << 4)); \
    } \
    _Pragma("unroll") \
    for (int ni = 0; ni < 2; ++ni) { \
      int R = (NH)*128 + wno + ni*16 + lr; \
      bfq[ni][0] = *(const bf16x8*)(sBb + R*128 + ((g ^ lb) << 4)); \
      bfq[ni][1] = *(const bf16x8*)(sBb + R*128 + (((4 + g) ^ lb) << 4)); \
    } \
    STAGES; \
    VMW; \
    __builtin_amdgcn_sched_barrier(0); \
    __builtin_amdgcn_s_barrier(); \
    asm volatile("s_waitcnt lgkmcnt(0)" ::: "memory"); \
    __builtin_amdgcn_sched_barrier(0); \
    __builtin_amdgcn_s_setprio(1); \
    _Pragma("unroll") \
    for (int mi = 0; mi < 4; ++mi) \
      _Pragma("unroll") \
      for (int ni = 0; ni < 2; ++ni) { \
        acc[MH][NH][mi][ni] = __builtin_amdgcn_mfma_f32_16x16x32_bf16( \
            af[mi][0], bfq[ni][0], acc[MH][NH][mi][ni], 0, 0, 0); \
        acc[MH][NH][mi][ni] = __builtin_amdgcn_mfma_f32_16x16x32_bf16( \
            af[mi][1], bfq[ni][1], acc[MH][NH][mi][ni], 0, 0, 0); \
      } \
    __builtin_amdgcn_s_setprio(0); \
    __builtin_amdgcn_s_barrier(); \
  } while (0)

  f32x4 zz = {0.f, 0.f, 0.f, 0.f};
  f32x4 acc[2][2][4][2];
  #pragma unroll
  for (int a = 0; a < 2; ++a)
    #pragma unroll
    for (int b = 0; b < 2; ++b)
      #pragma unroll
      for (int c = 0; c < 4; ++c)
        #pragma unroll
        for (int d = 0; d < 2; ++d) acc[a][b][c][d] = zz;

  // prologue: tile0 full -> buf0 (8 loads), tile1 Ah0+Bh0 -> buf1 (4 loads)
  STAGE_A(0, 0, 0, 0); STAGE_A(0, 0, 1, 0);
  STAGE_B(0, 0, 0, 0); STAGE_B(0, 0, 1, 0);
  STAGE_A(0, 1, 0, 0); STAGE_A(0, 1, 1, 0);
  STAGE_B(0, 1, 0, 0); STAGE_B(0, 1, 1, 0);
  STAGE_A(1, 0, 0, 1); STAGE_A(1, 0, 1, 1);
  STAGE_B(1, 0, 0, 1); STAGE_B(1, 0, 1, 1);
  asm volatile("s_waitcnt vmcnt(4)" ::: "memory");   // tile0 landed
  __builtin_amdgcn_s_barrier();

  for (int i = 0; i < 32; ++i) {
    const int t1 = 2 * i + 1;
    const int t2 = (2 * i + 2) & 63;
    const int t3 = (2 * i + 3) & 63;
    PHASE(0, 0, 0, { STAGE_A(1,1,0,t1); STAGE_A(1,1,1,t1); STAGE_B(1,1,0,t1); STAGE_B(1,1,1,t1); }, VMN);
    PHASE(0, 1, 0, {}, VMN);
    PHASE(1, 0, 0, { STAGE_A(0,0,0,t2); STAGE_A(0,0,1,t2); }, VMN);
    PHASE(1, 1, 0, { STAGE_B(0,0,0,t2); STAGE_B(0,0,1,t2); }, VM4);
    PHASE(0, 0, 1, { STAGE_A(0,1,0,t2); STAGE_A(0,1,1,t2); STAGE_B(0,1,0,t2); STAGE_B(0,1,1,t2); }, VMN);
    PHASE(0, 1, 1, {}, VMN);
    PHASE(1, 0, 1, { STAGE_A(1,0,0,t3); STAGE_A(1,0,1,t3); }, VMN);
    PHASE(1, 1, 1, { STAGE_B(1,0,0,t3); STAGE_B(1,0,1,t3); }, VM4);
  }

  asm volatile("s_waitcnt vmcnt(0)" ::: "memory");

  const int g4 = g * 4;
  #pragma unroll
  for (int MH = 0; MH < 2; ++MH) {
    #pragma unroll
    for (int mi = 0; mi < 4; ++mi) {
      #pragma unroll
      for (int j = 0; j < 4; ++j) {
        int row = m0 + MH * 128 + wmo + mi * 16 + g4 + j;
        float qm = qmask[row] ? 1.f : 0.f;
        float fA = qm * (cmA ? 1.f : 0.f);
        float fB = qm * (cmB ? 1.f : 0.f);
        #pragma unroll
        for (int NH = 0; NH < 2; ++NH) {
          float fc = NH ? fB : fA;
          #pragma unroll
          for (int ni = 0; ni < 2; ++ni) {
            int col = n0 + NH * 128 + wno + ni * 16 + lr;
            out[(size_t)row * OUT_F + col] =
                (acc[MH][NH][mi][ni][j] + bias[col]) * fc;
          }
        }
      }
    }
  }
#undef PHASE
#undef STAGE_A
#undef STAGE_B
#undef VM4
#undef VMN
}

extern "C" void kernel_launch(void* const* d_in, const int* in_sizes, int n_in,
                              void* d_out, int out_size, void* d_ws, size_t ws_size,
                              hipStream_t stream) {
  const float* x = (const float*)d_in[0];
  const float* codebooks = (const float*)d_in[1];
  const float* bias = (const float*)d_in[2];
  const float* lnw = (const float*)d_in[3];
  const int* codes = (const int*)d_in[4];       // [32][4096]
  const int* centroids = (const int*)d_in[5];   // [32][32]
  float* out = (float*)d_out;

  char* ws = (char*)d_ws;
  int* cmask = (int*)(ws + OFF_CMASK);
  int* qtile = (int*)(ws + OFF_QTILE);
  int* qmask = (int*)(ws + OFF_QMASK);
  uint4* whi = (uint4*)(ws + OFF_WHI);
  uint4* wlo = (uint4*)(ws + OFF_WLO);
  __hip_bfloat16* xb = (__hip_bfloat16*)(ws + OFF_XB);
  __hip_bfloat16* wb = (__hip_bfloat16*)(ws + OFF_WB);

  hipLaunchKernelGGL(k0b_fragw, dim3(64), dim3(256), 0, stream,
                     codebooks, centroids, whi, wlo, cmask, qtile);
  hipLaunchKernelGGL(k1b_dots, dim3(256), dim3(512), 0, stream,
                     x, whi, wlo, lnw, qmask, cmask, qtile);
  hipLaunchKernelGGL(k1a_convert, dim3(2048), dim3(256), 0, stream,
                     x, xb);
  hipLaunchKernelGGL(k2_expand_w, dim3(4096), dim3(256), 0, stream,
                     codebooks, codes, wb);
  hipLaunchKernelGGL(k3_gemm, dim3(512), dim3(512), 0, stream,
                     xb, wb, bias, qmask, cmask, qtile, out);
}